// Round 4
// baseline (5147.275 us; speedup 1.0000x reference)
//
#include <hip/hip_runtime.h>
#include <cstdint>
#include <cstddef>

// ---------------------------------------------------------------------------
// Problem constants
// ---------------------------------------------------------------------------
#define BB 32      // batch
#define TT 512     // seq len
#define DD 512     // emb dim
#define HH 512     // lstm size
#define DIRS 10    // 5 stacks x {fw,bw}
#define HSZ ((size_t)DIRS * BB * HH)     // elems per h ping-pong buffer
#define LWPITCH 520                      // 512 + 8 pad u16 (16B-aligned rows)
#define REDPITCH 66                      // 64 + 2 pad floats (epilogue gather <=4-way)
#define SMEM_REC (128 * LWPITCH * 2 + 64 * REDPITCH * 4)   // 133120 + 16896 = 150016

typedef unsigned short u16;
typedef __attribute__((ext_vector_type(8))) short short8;   // 8 x bf16 (4 VGPRs)
typedef __attribute__((ext_vector_type(4))) float f32x4;    // MFMA accum

__device__ __forceinline__ u16 f2b(float f) {
    union { float f; unsigned u; } v; v.f = f;
    unsigned u = v.u;
    u = (u + 0x7FFFu + ((u >> 16) & 1u)) >> 16;   // RNE
    return (u16)u;
}
__device__ __forceinline__ float b2f(u16 b) {
    union { unsigned u; float f; } v; v.u = ((unsigned)b) << 16;
    return v.f;
}
__device__ __forceinline__ float sigm(float x) { return 1.f / (1.f + __expf(-x)); }
__device__ __forceinline__ float tanh_(float x) { return 1.f - 2.f / (1.f + __expf(2.f * x)); }
__device__ __forceinline__ f32x4 fzero() { f32x4 z = {0.f, 0.f, 0.f, 0.f}; return z; }

// Coherent 16B load (LLC, vmcnt-tracked). RULE (round-3 lesson): the result
// registers are COMPILER-INVISIBLE in-flight values — they must be consumed
// within the same phase, after an explicit s_waitcnt vmcnt(0)+sched_barrier,
// and must NEVER be live across a __syncthreads (spill of an in-flight reg
// stores garbage).
__device__ __forceinline__ uint4 load_coh16(const u16* p) {
    uint4 r;
    asm volatile("global_load_dwordx4 %0, %1, off sc0 sc1"
                 : "=v"(r) : "v"(p) : "memory");
    return r;
}

// ---------------------------------------------------------------------------
// K1: x fp32 -> bf16
// ---------------------------------------------------------------------------
__global__ void k_convx(const float* __restrict__ X, u16* __restrict__ XB) {
    int i = blockIdx.x * 256 + threadIdx.x;
    if (i >= (BB * TT * DD) / 4) return;
    float4 v = ((const float4*)X)[i];
    unsigned lo = (unsigned)f2b(v.x) | ((unsigned)f2b(v.y) << 16);
    unsigned hi = (unsigned)f2b(v.z) | ((unsigned)f2b(v.w) << 16);
    uint2 o; o.x = lo; o.y = hi;
    ((uint2*)XB)[i] = o;
}

// ---------------------------------------------------------------------------
// K2: build WT[d][n][k] = W_src[s][k][n] (bf16), LDS-tiled transpose.
// ---------------------------------------------------------------------------
__global__ void k_wt(const float* __restrict__ Wf, const float* __restrict__ Wb,
                     u16* __restrict__ WT) {
    int d = blockIdx.z, s = d >> 1;
    const float* src = (d & 1) ? Wb : Wf;   // [5][1024][2048]
    __shared__ float tile[32][33];
    int tx = threadIdx.x & 31, ty = threadIdx.x >> 5;
    int kt = blockIdx.x, nt = blockIdx.y;
#pragma unroll
    for (int r = 0; r < 4; r++) {
        int k = kt * 32 + ty + r * 8, n = nt * 32 + tx;
        tile[ty + r * 8][tx] = src[((size_t)s * 1024 + k) * 2048 + n];
    }
    __syncthreads();
#pragma unroll
    for (int r = 0; r < 4; r++) {
        int n = nt * 32 + ty + r * 8, k = kt * 32 + tx;
        WT[((size_t)d * 2048 + n) * 1024 + k] = f2b(tile[tx][ty + r * 8]);
    }
}

// ---------------------------------------------------------------------------
// K3: build head weight WBT[64 c][5120 k] bf16 + bias B64[64].
// ---------------------------------------------------------------------------
__global__ void k_wbt(const float* W1, const float* W2, const float* W3, const float* W4,
                      const float* b1, const float* b2, const float* b3, const float* b4,
                      u16* __restrict__ WBT, float* __restrict__ B64) {
    int idx = blockIdx.x * 256 + threadIdx.x;
    const int off[4] = {0, 17, 26, 51};
    const int tg[4]  = {17, 9, 25, 13};
    if (idx < 64) {
        int c = idx;
        int ti = (c < 17) ? 0 : (c < 26) ? 1 : (c < 51) ? 2 : 3;
        const float* bbp[4] = {b1, b2, b3, b4};
        B64[c] = bbp[ti][c - off[ti]];
    }
    if (idx >= 64 * 5120) return;
    int c = idx / 5120, k = idx % 5120;
    int ti = (c < 17) ? 0 : (c < 26) ? 1 : (c < 51) ? 2 : 3;
    const float* Ws[4] = {W1, W2, W3, W4};
    int tag = c - off[ti];
    float v;
    if (k < 4096) {
        int i = k >> 10, kk = k & 1023;
        v = (i == ti) ? Ws[ti][(size_t)kk * tg[ti] + tag] : 0.f;
    } else {
        int kk = k - 4096;
        v = Ws[ti][(size_t)(1024 + kk) * tg[ti] + tag];
    }
    WBT[(size_t)c * 5120 + k] = f2b(v);
}

// ---------------------------------------------------------------------------
// K5: persistent recurrence kernel — 2 dirs per block.
//   Block blk = s*32 + jj serves dirs {2s (fw), 2s+1 (bw)}, 16 n-units each.
//   Per iteration t: phase A (fw step t) then phase B (bw step t). While
//   dir A's h(t+1) propagates through the LLC, the block computes dir B.
//   ROUND-4 LOAD DISCIPLINE (fix for round-2/3 corruption): every value
//   that is live across a barrier is loaded through COMPILER-VISIBLE ops
//   (plain loads / __hip_atomic_load) so spills are safe. Only the h loads
//   use asm (coherent 16B), with an issue->drain->consume range that stays
//   inside one phase.
// ---------------------------------------------------------------------------
__global__ __launch_bounds__(512, 2) void k_rec(
    const u16* __restrict__ WT, const u16* __restrict__ XB,
    const float* __restrict__ bfw, const float* __restrict__ bbw,
    u16* __restrict__ Hbuf, u16* __restrict__ OUTS,
    const int* __restrict__ lens, unsigned* __restrict__ flg)
{
    extern __shared__ char smem[];
    u16* lWx = (u16*)smem;                               // [128][LWPITCH] bf16: [dir][g4*16+u][k<512]
    float* red = (float*)(smem + 128 * LWPITCH * 2);     // [64][REDPITCH] f32

    int blk = blockIdx.x, s = blk >> 5, jj = blk & 31, d0 = s * 2;
    int tid = threadIdx.x, w = tid >> 6, lane = tid & 63, quad = lane >> 4, l15 = lane & 15;
    int gsel = w & 1, mtile = (w >> 1) & 1, khalf = w >> 2;

    // ---- stage W_x slices for BOTH dirs into LDS (once) ----
#pragma unroll
    for (int it = 0; it < 16; ++it) {
        int g16 = it * 512 + tid;          // 8192 granules of 16B
        int row = g16 >> 6, c = g16 & 63;  // row 0..127, 64x16B per row
        int dq = row >> 6, local = row & 63;
        int n = (local >> 4) * 512 + jj * 16 + (local & 15);
        const u16* src = WT + ((size_t)(d0 + dq) * 2048 + n) * 1024 + c * 8;  // x half k<512
        *(uint4*)(lWx + row * LWPITCH + c * 8) = *(const uint4*)src;
    }

    // ---- W_h fragments, both dirs: persistent registers/AGPRs ----
    short8 Bf[2][8][2];
#pragma unroll
    for (int dd = 0; dd < 2; dd++)
#pragma unroll
        for (int ks = 0; ks < 8; ks++)
#pragma unroll
            for (int gb = 0; gb < 2; gb++) {
                int n = (gsel * 2 + gb) * 512 + jj * 16 + l15;
                int k = 512 + khalf * 256 + ks * 32 + quad * 8;
                Bf[dd][ks][gb] = *(const short8*)(WT + ((size_t)(d0 + dd) * 2048 + n) * 1024 + k);
            }

    // ---- persistent per-lane state ----
    int bA = mtile * 16 + l15;             // A-fragment batch row
    int lbA = lens[bA];
    int cb = tid >> 4, cu = tid & 15;      // epilogue cell: batch cb, unit cu
    int lbC = lens[cb];
    int myq = (cb >> 2) & 3, myr = cb & 3, mym = cb >> 4;
    float cst[2] = {0.f, 0.f}, hpv[2] = {0.f, 0.f};
    float bv[2][4];
#pragma unroll
    for (int dd = 0; dd < 2; dd++) {
        const float* bias = (dd ? bbw : bfw) + (size_t)s * 2048;
#pragma unroll
        for (int g4 = 0; g4 < 4; g4++) bv[dd][g4] = bias[g4 * 512 + jj * 16 + cu];
    }

    unsigned fpre = 0;                     // t=0 target is 0: always passes

    __syncthreads();   // lWx ready

    for (int t = 0; t < TT; ++t) {
#pragma unroll
        for (int dd = 0; dd < 2; ++dd) {
            int d = d0 + dd;
            unsigned tgt = (unsigned)t;

            // ---- poll (compiler-visible atomic loads; usually satisfied
            //      by the prefetched fpre) ----
            if (!__all((int)(fpre >= tgt))) {
                const unsigned* fp = flg + (size_t)d * 64;
                // bounded: protocol failure => wrong results, never a hang
                for (int spin = 0; spin < (1 << 21); ++spin) {
                    unsigned f = 0xFFFFFFFFu;
                    if (lane < 32)
                        f = __hip_atomic_load(fp + lane, __ATOMIC_RELAXED,
                                              __HIP_MEMORY_SCOPE_AGENT);
                    if (__all((int)(f >= tgt))) break;
                    __builtin_amdgcn_s_sleep(2);
                }
            }

            // ---- x loads (plain, compiler-tracked) ----
            int srcT = dd ? ((t < lbA) ? (lbA - 1 - t) : t) : t;
            const u16* xrow = XB + ((size_t)bA * TT + srcT) * DD + khalf * 256;
            uint4 xraw[8];
#pragma unroll
            for (int ks = 0; ks < 8; ks++)
                xraw[ks] = *(const uint4*)(xrow + ks * 32 + quad * 8);

            // ---- A_h coherent loads (asm): issue all 8 together ----
            const u16* hin = Hbuf + (size_t)(t & 1) * HSZ + (size_t)d * BB * HH;
            uint4 araw[8];
#pragma unroll
            for (int ks = 0; ks < 8; ks++)
                araw[ks] = load_coh16(hin + (size_t)bA * HH + khalf * 256 + ks * 32 + quad * 8);

            f32x4 acc[2];
            acc[0] = fzero(); acc[1] = fzero();

            // ---- x-GEMM from LDS weights ----
#pragma unroll
            for (int ks = 0; ks < 8; ks++) {
                short8 a = *(const short8*)(&xraw[ks]);
#pragma unroll
                for (int gb = 0; gb < 2; gb++) {
                    int row = dd * 64 + (gsel * 2 + gb) * 16 + l15;
                    short8 bfr = *(const short8*)(lWx + row * LWPITCH
                                                  + khalf * 256 + ks * 32 + quad * 8);
                    acc[gb] = __builtin_amdgcn_mfma_f32_16x16x32_bf16(a, bfr, acc[gb], 0, 0, 0);
                }
            }

            // drain the asm h loads, then h-GEMM (rule #18 fence)
            asm volatile("s_waitcnt vmcnt(0)" ::: "memory");
            __builtin_amdgcn_sched_barrier(0);
#pragma unroll
            for (int ks = 0; ks < 8; ks++) {
                short8 a = *(const short8*)(&araw[ks]);
#pragma unroll
                for (int gb = 0; gb < 2; gb++)
                    acc[gb] = __builtin_amdgcn_mfma_f32_16x16x32_bf16(a, Bf[dd][ks][gb], acc[gb], 0, 0, 0);
            }

            // ---- khalf-partial exchange: every wave writes its acc ----
#pragma unroll
            for (int gb = 0; gb < 2; gb++)
#pragma unroll
                for (int r = 0; r < 4; r++) {
                    int R = (((khalf * 2 + gsel) * 2 + gb) * 2 + mtile) * 4 + r;
                    red[R * REDPITCH + lane] = acc[gb][r];
                }
            __syncthreads();

            // ---- epilogue: 1 cell per thread ----
            float z[4];
#pragma unroll
            for (int g4 = 0; g4 < 4; g4++) {
                int gs = g4 >> 1, gb = g4 & 1;
                int R0 = (((0 * 2 + gs) * 2 + gb) * 2 + mym) * 4 + myr;
                int R1 = (((1 * 2 + gs) * 2 + gb) * 2 + mym) * 4 + myr;
                z[g4] = red[R0 * REDPITCH + myq * 16 + cu]
                      + red[R1 * REDPITCH + myq * 16 + cu] + bv[dd][g4];
            }
            float cn = sigm(z[2] + 1.f) * cst[dd] + sigm(z[0]) * tanh_(z[1]);
            float hn = sigm(z[3]) * tanh_(cn);
            bool act = t < lbC;
            if (act) cst[dd] = cn;
            u16 hv = f2b(act ? hn : hpv[dd]);
            hpv[dd] = b2f(hv);
            u16* hout = Hbuf + (size_t)((t + 1) & 1) * HSZ + (size_t)d * BB * HH;
            __hip_atomic_store(&hout[(size_t)cb * HH + jj * 16 + cu], hv,
                               __ATOMIC_RELAXED, __HIP_MEMORY_SCOPE_AGENT);
            int twr = dd ? (act ? (lbC - 1 - t) : t) : t;   // fused reverse scatter
            OUTS[(((size_t)s * BB + cb) * TT + twr) * 1024 + dd * 512 + jj * 16 + cu]
                = f2b(act ? hn : 0.f);

            // ---- prefetch next phase's flag line (compiler-visible) ----
            int ndd = dd ^ 1;
            fpre = 0xFFFFFFFFu;
            if (lane < 32)
                fpre = __hip_atomic_load(flg + (size_t)(d0 + ndd) * 64 + lane,
                                         __ATOMIC_RELAXED, __HIP_MEMORY_SCOPE_AGENT);

            // stores drained by the barrier's vmcnt(0); then tid0 publishes
            __syncthreads();
            if (tid == 0)
                __hip_atomic_store(flg + (size_t)d * 64 + jj, (unsigned)(t + 1),
                                   __ATOMIC_RELAXED, __HIP_MEMORY_SCOPE_AGENT);
        }
    }
}

// ---------------------------------------------------------------------------
// K6: heads. logits[16384, 64] = U[16384, 5120] @ WBT^T + B64.
// ---------------------------------------------------------------------------
__global__ __launch_bounds__(256) void k_head(
    const u16* __restrict__ OUTS, const u16* __restrict__ WBT,
    const float* __restrict__ B64, float* __restrict__ OUT)
{
    int tid = threadIdx.x, w = tid >> 6, lane = tid & 63, quad = lane >> 4, l15 = lane & 15;
    int mtile = blockIdx.x * 4 + w, r0 = mtile * 16;
    int row_a = r0 + l15, ba = row_a >> 9, ta = row_a & 511;
    f32x4 acc[4];
#pragma unroll
    for (int ni = 0; ni < 4; ni++) acc[ni] = fzero();

    for (int k0 = 0; k0 < 5120; k0 += 32) {
        int kidx = k0 + quad * 8;
        int blkk = kidx >> 10, kk = kidx & 1023;
        short8 a = *(const short8*)(OUTS + (((size_t)blkk * BB + ba) * TT + ta) * 1024 + kk);
#pragma unroll
        for (int ni = 0; ni < 4; ni++) {
            short8 bf = *(const short8*)(WBT + (size_t)(ni * 16 + l15) * 5120 + kidx);
            acc[ni] = __builtin_amdgcn_mfma_f32_16x16x32_bf16(a, bf, acc[ni], 0, 0, 0);
        }
    }
#pragma unroll
    for (int ni = 0; ni < 4; ni++) {
        int c = ni * 16 + l15;
        float bv = B64[c];
#pragma unroll
        for (int r = 0; r < 4; r++) {
            int row = r0 + quad * 4 + r;
            OUT[(size_t)row * 64 + c] = acc[ni][r] + bv;
        }
    }
}

// ---------------------------------------------------------------------------
extern "C" void kernel_launch(void* const* d_in, const int* in_sizes, int n_in,
                              void* d_out, int out_size, void* d_ws, size_t ws_size,
                              hipStream_t stream) {
    const float* X   = (const float*)d_in[0];
    const int* lens  = (const int*)d_in[1];
    const float* Wf  = (const float*)d_in[2];
    const float* bf_ = (const float*)d_in[3];
    const float* Wb  = (const float*)d_in[4];
    const float* bb_ = (const float*)d_in[5];
    const float* W1  = (const float*)d_in[6];
    const float* b1  = (const float*)d_in[7];
    const float* W2  = (const float*)d_in[8];
    const float* b2  = (const float*)d_in[9];
    const float* W3  = (const float*)d_in[10];
    const float* b3  = (const float*)d_in[11];
    const float* W4  = (const float*)d_in[12];
    const float* b4  = (const float*)d_in[13];

    // ---- runtime workspace layout ----
    char* ws = (char*)d_ws;
    size_t off = 0;
    auto take = [&](size_t bytes) { size_t o = off; off += (bytes + 255) & ~(size_t)255; return o; };
    size_t wtOff   = take((size_t)DIRS * 2048 * 1024 * 2);
    size_t xbOff   = take((size_t)BB * TT * DD * 2);
    size_t outsOff = take((size_t)5 * BB * TT * 1024 * 2);
    size_t hOff    = take((size_t)2 * HSZ * 2);
    size_t flgOff  = take((size_t)DIRS * 64 * 4);      // 32 flags + pad per dir (1 line)
    size_t wbtOff  = take((size_t)64 * 5120 * 2);
    size_t b64Off  = take((size_t)64 * 4);

    u16* WT    = (u16*)(ws + wtOff);
    u16* XB    = (u16*)(ws + xbOff);
    u16* OUTS  = (u16*)(ws + outsOff);
    u16* Hbuf  = (u16*)(ws + hOff);
    unsigned* FLG = (unsigned*)(ws + flgOff);
    u16* WBT   = (u16*)(ws + wbtOff);
    float* B64 = (float*)(ws + b64Off);

    // zero the ENTIRE [H | FLG] span (flags MUST reset each launch;
    // round-3 lesson: short memset = race)
    hipMemsetAsync(ws + hOff, 0, wbtOff - hOff, stream);

    // 150 KB dynamic LDS for the persistent kernel
    (void)hipFuncSetAttribute((const void*)k_rec,
                              hipFuncAttributeMaxDynamicSharedMemorySize, SMEM_REC);

    k_convx<<<8192, 256, 0, stream>>>(X, XB);
    k_wt<<<dim3(32, 64, 10), 256, 0, stream>>>(Wf, Wb, WT);
    k_wbt<<<1280, 256, 0, stream>>>(W1, W2, W3, W4, b1, b2, b3, b4, WBT, B64);

    // one persistent dispatch: 160 blocks = 5 stacks x 32 jj, 2 dirs/block
    k_rec<<<160, 512, SMEM_REC, stream>>>(WT, XB, bf_, bb_, Hbuf, OUTS, lens, FLG);

    k_head<<<256, 256, 0, stream>>>(OUTS, WBT, B64, (float*)d_out);
}